// Round 15
// baseline (135.674 us; speedup 1.0000x reference)
//
#include <hip/hip_runtime.h>
#include <hip/hip_bf16.h>
#include <cstdint>

constexpr int kS  = 384;
constexpr int kB  = 2;
constexpr int kC  = 768;
constexpr int kH  = 12;
constexpr int kCC = 64;
constexpr int kHPB = 4;  // heads per attention block

typedef __attribute__((ext_vector_type(8))) short short8;
typedef __attribute__((ext_vector_type(4))) float f32x4;
typedef __attribute__((ext_vector_type(4))) unsigned short u16x4;
typedef const __attribute__((address_space(1))) unsigned int glb_u32_t;
typedef __attribute__((address_space(3))) unsigned int lds_u32_t;

static __device__ __forceinline__ ushort f2bf(float f) {
  __hip_bfloat16 h = __float2bfloat16(f);
  return *reinterpret_cast<ushort*>(&h);
}
static __device__ __forceinline__ float bf2f(ushort x) {
  unsigned v = (unsigned)x << 16;
  return __builtin_bit_cast(float, v);
}

// VALU-pipe butterfly add over the 16-lane row (DPP). R13-proven.
template <int CTRL>
static __device__ __forceinline__ float dpp_add(float x) {
  int xi = __builtin_bit_cast(int, x);
  int yi = __builtin_amdgcn_update_dpp(0, xi, CTRL, 0xF, 0xF, true);
  return x + __builtin_bit_cast(float, yi);
}
static __device__ __forceinline__ float row16_sum(float x) {
  x = dpp_add<0xB1>(x);
  x = dpp_add<0x4E>(x);
  x = dpp_add<0x124>(x);
  x = dpp_add<0x128>(x);
  return x;
}

// ---------------------------------------------------------------------------
// One-shot f32 -> bf16 conversion of x, qkv_w, out_w (float4-granular).
// ---------------------------------------------------------------------------
__global__ __launch_bounds__(256) void convert_bf16(
    const float* __restrict__ x, const float* __restrict__ qw,
    const float* __restrict__ ow, ushort* __restrict__ xb,
    ushort* __restrict__ qwb, ushort* __restrict__ owb) {
  int idx = blockIdx.x * 256 + threadIdx.x;
  const float* src;
  ushort* dst;
  if (idx < 147456) {
    src = x; dst = xb;
  } else if (idx < 147456 + 442368) {
    idx -= 147456; src = qw; dst = qwb;
  } else {
    idx -= 589824; src = ow; dst = owb;
  }
  f32x4 v = *reinterpret_cast<const f32x4*>(src + (size_t)idx * 4);
  u16x4 o;
  o[0] = f2bf(v[0]); o[1] = f2bf(v[1]); o[2] = f2bf(v[2]); o[3] = f2bf(v[3]);
  *reinterpret_cast<u16x4*>(dst + (size_t)idx * 4) = o;
}

// ---------------------------------------------------------------------------
// qkv-projection GEMM (R13 single-buffer) with split epilogue:
//   q -> qbuf f32  AND  quB = bf16(q + u)  (feeds the dd MFMA kernel)
//   k -> kbuf bf16, v -> vbuf bf16 (compact, L2-resident)
// Tile 64x64, BK=64, 4 waves 2x2.
// ---------------------------------------------------------------------------
__global__ __launch_bounds__(256) void gemm_qkv(
    const ushort* __restrict__ Abf, const ushort* __restrict__ Wbf,
    const float* __restrict__ bias, const float* __restrict__ u,
    float* __restrict__ qbuf, ushort* __restrict__ quB,
    ushort* __restrict__ kbuf, ushort* __restrict__ vbuf, int K) {
  __shared__ ushort As[64 * 64];
  __shared__ ushort Ws[64 * 64];
  const int tid = threadIdx.x;
  const int m0 = blockIdx.y * 64, n0 = blockIdx.x * 64;
  const int wv = tid >> 6, l = tid & 63;
  const int wr = wv >> 1, wc = wv & 1;
  const int lr = l & 15, lk = l >> 4;

  f32x4 acc[2][2] = {{{0.f, 0.f, 0.f, 0.f}, {0.f, 0.f, 0.f, 0.f}},
                     {{0.f, 0.f, 0.f, 0.f}, {0.f, 0.f, 0.f, 0.f}}};

  for (int k0 = 0; k0 < K; k0 += 64) {
    __syncthreads();
#pragma unroll
    for (int j = 0; j < 2; ++j) {
      int cid = (j * 4 + wv) * 64 + l;     // 16B chunk id, 0..511
      int r = cid >> 3, c = cid & 7;
      int cs = c ^ (r & 7);                // inverse-swizzled source chunk
      const ushort* ga = Abf + (size_t)(m0 + r) * K + k0 + cs * 8;
      __builtin_amdgcn_global_load_lds((glb_u32_t*)ga,
                                       (lds_u32_t*)&As[(cid & ~63) * 8],
                                       16, 0, 0);
      const ushort* gw = Wbf + (size_t)(n0 + r) * K + k0 + cs * 8;
      __builtin_amdgcn_global_load_lds((glb_u32_t*)gw,
                                       (lds_u32_t*)&Ws[(cid & ~63) * 8],
                                       16, 0, 0);
    }
    __syncthreads();
#pragma unroll
    for (int ks = 0; ks < 2; ++ks) {
      short8 af[2], bw[2];
#pragma unroll
      for (int f = 0; f < 2; ++f) {
        int ra = wr * 32 + f * 16 + lr;
        int ca = (ks * 4 + lk) ^ (ra & 7);
        af[f] = *reinterpret_cast<const short8*>(&As[(ra * 8 + ca) * 8]);
        int rb = wc * 32 + f * 16 + lr;
        int cb = (ks * 4 + lk) ^ (rb & 7);
        bw[f] = *reinterpret_cast<const short8*>(&Ws[(rb * 8 + cb) * 8]);
      }
#pragma unroll
      for (int fr = 0; fr < 2; ++fr)
#pragma unroll
        for (int fc = 0; fc < 2; ++fc)
          acc[fr][fc] = __builtin_amdgcn_mfma_f32_16x16x32_bf16(
              af[fr], bw[fc], acc[fr][fc], 0, 0, 0);
    }
  }

  const int seg = n0 / kC;          // 0=q, 1=k, 2=v (block-uniform)
  const int nc0 = n0 - seg * kC;
#pragma unroll
  for (int fr = 0; fr < 2; ++fr)
#pragma unroll
    for (int fc = 0; fc < 2; ++fc)
#pragma unroll
      for (int j = 0; j < 4; ++j) {
        int m = m0 + wr * 32 + fr * 16 + lk * 4 + j;
        int n = nc0 + wc * 32 + fc * 16 + lr;
        float val = acc[fr][fc][j] + bias[seg * kC + n];
        if (seg == 0) {
          qbuf[(size_t)m * kC + n] = val;
          quB[(size_t)m * kC + n] = f2bf(val + u[n]);
        } else {
          int t = m >> 1, bb = m & 1;
          ushort* dst = (seg == 1) ? kbuf : vbuf;
          dst[((size_t)bb * kS + t) * kC + n] = f2bf(val);
        }
      }
}

// ---------------------------------------------------------------------------
// dd = (q+u) . k  batched MFMA GEMM. Block = (t_tile, s_tile, b*12+h);
// lower-triangle tiles only. Output bf16 dd[b*12+h][s][t] (unscaled).
// ---------------------------------------------------------------------------
__global__ __launch_bounds__(256) void dd_gemm(
    const ushort* __restrict__ quB, const ushort* __restrict__ kbuf,
    ushort* __restrict__ dd) {
  const int tt = blockIdx.x, st = blockIdx.y, bh = blockIdx.z;
  if (tt > st) return;  // fully-masked tile: never read downstream
  const int b = bh / kH, h = bh % kH;

  __shared__ ushort Aq[64 * 64];
  __shared__ ushort Bk[64 * 64];
  const int tid = threadIdx.x;
  const int wv = tid >> 6, l = tid & 63;
  const int wr = wv >> 1, wc = wv & 1;
  const int lr = l & 15, lk = l >> 4;

  // stage A (q+u rows = s) and B (k rows = t), 64x64 bf16 each, swizzled src
#pragma unroll
  for (int j = 0; j < 2; ++j) {
    int cid = (j * 4 + wv) * 64 + l;   // 0..511
    int r = cid >> 3, c = cid & 7;
    int cs = c ^ (r & 7);
    const ushort* ga =
        quB + (size_t)((st * 64 + r) * kB + b) * kC + h * kCC + cs * 8;
    __builtin_amdgcn_global_load_lds((glb_u32_t*)ga,
                                     (lds_u32_t*)&Aq[(cid & ~63) * 8],
                                     16, 0, 0);
    const ushort* gk =
        kbuf + ((size_t)b * kS + tt * 64 + r) * kC + h * kCC + cs * 8;
    __builtin_amdgcn_global_load_lds((glb_u32_t*)gk,
                                     (lds_u32_t*)&Bk[(cid & ~63) * 8],
                                     16, 0, 0);
  }
  __syncthreads();

  f32x4 acc[2][2] = {{{0.f, 0.f, 0.f, 0.f}, {0.f, 0.f, 0.f, 0.f}},
                     {{0.f, 0.f, 0.f, 0.f}, {0.f, 0.f, 0.f, 0.f}}};
#pragma unroll
  for (int ks = 0; ks < 2; ++ks) {
    short8 af[2], bw[2];
#pragma unroll
    for (int f = 0; f < 2; ++f) {
      int ra = wr * 32 + f * 16 + lr;
      int ca = (ks * 4 + lk) ^ (ra & 7);
      af[f] = *reinterpret_cast<const short8*>(&Aq[(ra * 8 + ca) * 8]);
      int rb = wc * 32 + f * 16 + lr;
      int cb = (ks * 4 + lk) ^ (rb & 7);
      bw[f] = *reinterpret_cast<const short8*>(&Bk[(rb * 8 + cb) * 8]);
    }
#pragma unroll
    for (int fr = 0; fr < 2; ++fr)
#pragma unroll
      for (int fc = 0; fc < 2; ++fc)
        acc[fr][fc] = __builtin_amdgcn_mfma_f32_16x16x32_bf16(
            af[fr], bw[fc], acc[fr][fc], 0, 0, 0);
  }

  ushort* drow = dd + (size_t)bh * kS * kS;
#pragma unroll
  for (int fr = 0; fr < 2; ++fr)
#pragma unroll
    for (int fc = 0; fc < 2; ++fc)
#pragma unroll
      for (int j = 0; j < 4; ++j) {
        int s = st * 64 + wr * 32 + fr * 16 + lk * 4 + j;
        int t = tt * 64 + wc * 32 + fc * 16 + lr;
        drow[(size_t)s * kS + t] = f2bf(acc[fr][fc][j]);
      }
}

// ---------------------------------------------------------------------------
// MFMA bf16 GEMM (R13 single-buffer), f32 output + bias (out-projection).
// ---------------------------------------------------------------------------
__global__ __launch_bounds__(256) void gemm_bf16_lds(
    const ushort* __restrict__ Abf, const ushort* __restrict__ Wbf,
    const float* __restrict__ bias, float* __restrict__ Cg,
    int M, int N, int K) {
  __shared__ ushort As[64 * 64];
  __shared__ ushort Ws[64 * 64];
  const int tid = threadIdx.x;
  const int m0 = blockIdx.y * 64, n0 = blockIdx.x * 64;
  const int wv = tid >> 6, l = tid & 63;
  const int wr = wv >> 1, wc = wv & 1;
  const int lr = l & 15, lk = l >> 4;

  f32x4 acc[2][2] = {{{0.f, 0.f, 0.f, 0.f}, {0.f, 0.f, 0.f, 0.f}},
                     {{0.f, 0.f, 0.f, 0.f}, {0.f, 0.f, 0.f, 0.f}}};

  for (int k0 = 0; k0 < K; k0 += 64) {
    __syncthreads();
#pragma unroll
    for (int j = 0; j < 2; ++j) {
      int cid = (j * 4 + wv) * 64 + l;
      int r = cid >> 3, c = cid & 7;
      int cs = c ^ (r & 7);
      const ushort* ga = Abf + (size_t)(m0 + r) * K + k0 + cs * 8;
      __builtin_amdgcn_global_load_lds((glb_u32_t*)ga,
                                       (lds_u32_t*)&As[(cid & ~63) * 8],
                                       16, 0, 0);
      const ushort* gw = Wbf + (size_t)(n0 + r) * K + k0 + cs * 8;
      __builtin_amdgcn_global_load_lds((glb_u32_t*)gw,
                                       (lds_u32_t*)&Ws[(cid & ~63) * 8],
                                       16, 0, 0);
    }
    __syncthreads();
#pragma unroll
    for (int ks = 0; ks < 2; ++ks) {
      short8 af[2], bw[2];
#pragma unroll
      for (int f = 0; f < 2; ++f) {
        int ra = wr * 32 + f * 16 + lr;
        int ca = (ks * 4 + lk) ^ (ra & 7);
        af[f] = *reinterpret_cast<const short8*>(&As[(ra * 8 + ca) * 8]);
        int rb = wc * 32 + f * 16 + lr;
        int cb = (ks * 4 + lk) ^ (rb & 7);
        bw[f] = *reinterpret_cast<const short8*>(&Ws[(rb * 8 + cb) * 8]);
      }
#pragma unroll
      for (int fr = 0; fr < 2; ++fr)
#pragma unroll
        for (int fc = 0; fc < 2; ++fc)
          acc[fr][fc] = __builtin_amdgcn_mfma_f32_16x16x32_bf16(
              af[fr], bw[fc], acc[fr][fc], 0, 0, 0);
    }
  }

#pragma unroll
  for (int fr = 0; fr < 2; ++fr)
#pragma unroll
    for (int fc = 0; fc < 2; ++fc)
#pragma unroll
      for (int j = 0; j < 4; ++j) {
        int m = m0 + wr * 32 + fr * 16 + lk * 4 + j;
        int n = n0 + wc * 32 + fc * 16 + lr;
        Cg[(size_t)m * N + n] = acc[fr][fc][j] + bias[n];
      }
}

// ---------------------------------------------------------------------------
// Fused attention: two-pass, DPP reduce on VALU pipe, nt pe stream, compact
// bf16 v (L2-resident), dd scores precomputed by MFMA. Block = (s, b,
// head-group-of-4); 256 threads, wave = one head.
// ---------------------------------------------------------------------------
__global__ __launch_bounds__(256, 6) void attn_kernel(
    const float* __restrict__ qbuf, const float* __restrict__ pe,
    const ushort* __restrict__ dd, const ushort* __restrict__ vb,
    const float* __restrict__ w, ushort* __restrict__ obf) {
  __shared__ float sc[kHPB][kS];

  const int bid = blockIdx.x;
  const int sb = bid / (kH / kHPB);   // (s,b) index, s-descending
  const int hg = bid % (kH / kHPB);   // head group
  const int s = kS - 1 - (sb >> 1);   // big-s blocks first (load balance)
  const int b = sb & 1;
  const int wave = threadIdx.x >> 6;  // head within group
  const int h = hg * kHPB + wave;
  const int lane = threadIdx.x & 63;
  const int tq = lane >> 4;           // t-subgroup
  const int cq = (lane & 15) * 4;     // channel quad
  const int ch = h * kCC + cq;
  const float scale = 0.125f;         // 1/sqrt(64)

  const int row = s * kB + b;
  const f32x4 q4 = *(const f32x4*)&qbuf[(size_t)row * kC + ch];
  const f32x4 w4 = *(const f32x4*)&w[ch];
  const f32x4 qw = q4 + w4;

  const ushort* vbase = vb + ((size_t)b * kS) * kC + ch;
  const ushort* ddrow = dd + ((size_t)(b * kH + h) * kS + s) * kS;
  const float* pbase = pe + ((int64_t)s * kS * kB + b) * kC + ch;
  const int pstride = kB * kC;  // 1536

  const int nfull = (s + 1) & ~15;  // t's covered by the unrolled main loop

  // ---- pass 1: scores (pe stream + precomputed dd) ----
  int t0 = 0;
  for (; t0 < nfull; t0 += 16) {
    f32x4 p4[4];
#pragma unroll
    for (int i = 0; i < 4; ++i) {
      int t = t0 + i * 4 + tq;
      p4[i] = __builtin_nontemporal_load(
          (const f32x4*)&pbase[(int64_t)t * pstride]);
    }
#pragma unroll
    for (int i = 0; i < 4; ++i) {
      int t = t0 + i * 4 + tq;
      float r = qw[0] * p4[i][0] + qw[1] * p4[i][1] +
                qw[2] * p4[i][2] + qw[3] * p4[i][3];
      r = row16_sum(r);  // VALU pipe, not LDS pipe
      if ((lane & 15) == 0) sc[wave][t] = (r + bf2f(ddrow[t])) * scale;
    }
  }
  for (; t0 <= s; t0 += 4) {  // tail (<16 t's)
    int t = t0 + tq;
    int tc = (t <= s) ? t : s;  // clamp keeps loads in-bounds
    f32x4 p4 = __builtin_nontemporal_load(
        (const f32x4*)&pbase[(int64_t)tc * pstride]);
    float r = qw[0] * p4[0] + qw[1] * p4[1] + qw[2] * p4[2] + qw[3] * p4[3];
    r = row16_sum(r);
    if ((lane & 15) == 0 && t <= s)
      sc[wave][t] = (r + bf2f(ddrow[t])) * scale;
  }
  __syncthreads();

  // ---- softmax over t in [0, s] (wave owns its head's row) ----
  float mx = -1e30f;
  for (int t = lane; t <= s; t += 64) mx = fmaxf(mx, sc[wave][t]);
#pragma unroll
  for (int off = 32; off; off >>= 1) mx = fmaxf(mx, __shfl_xor(mx, off, 64));
  float sum = 0.f;
  for (int t = lane; t <= s; t += 64) {
    float e = __expf(sc[wave][t] - mx);
    sc[wave][t] = e;
    sum += e;
  }
#pragma unroll
  for (int off = 32; off; off >>= 1) sum += __shfl_xor(sum, off, 64);
  const float rden = 1.0f / sum;

  // ---- pass 2: o = p @ v ----
  f32x4 oa = {0.f, 0.f, 0.f, 0.f};
  t0 = 0;
  for (; t0 < nfull; t0 += 16) {
    u16x4 vd[4];
    float p[4];
#pragma unroll
    for (int i = 0; i < 4; ++i) {
      int t = t0 + i * 4 + tq;
      vd[i] = *(const u16x4*)&vbase[(size_t)t * kC];
      p[i] = sc[wave][t];
    }
#pragma unroll
    for (int i = 0; i < 4; ++i) {
      oa[0] += p[i] * bf2f(vd[i][0]); oa[1] += p[i] * bf2f(vd[i][1]);
      oa[2] += p[i] * bf2f(vd[i][2]); oa[3] += p[i] * bf2f(vd[i][3]);
    }
  }
  for (; t0 <= s; t0 += 4) {  // tail
    int t = t0 + tq;
    if (t <= s) {
      float p = sc[wave][t];
      u16x4 vd = *(const u16x4*)&vbase[(size_t)t * kC];
      oa[0] += p * bf2f(vd[0]); oa[1] += p * bf2f(vd[1]);
      oa[2] += p * bf2f(vd[2]); oa[3] += p * bf2f(vd[3]);
    }
  }
#pragma unroll
  for (int off = 16; off <= 32; off <<= 1) {
    oa[0] += __shfl_xor(oa[0], off);
    oa[1] += __shfl_xor(oa[1], off);
    oa[2] += __shfl_xor(oa[2], off);
    oa[3] += __shfl_xor(oa[3], off);
  }
  if (lane < 16) {
    u16x4 res;
    res[0] = f2bf(oa[0] * rden); res[1] = f2bf(oa[1] * rden);
    res[2] = f2bf(oa[2] * rden); res[3] = f2bf(oa[3] * rden);
    *reinterpret_cast<u16x4*>(&obf[(size_t)row * kC + ch]) = res;
  }
}

// ---------------------------------------------------------------------------
extern "C" void kernel_launch(void* const* d_in, const int* in_sizes, int n_in,
                              void* d_out, int out_size, void* d_ws,
                              size_t ws_size, hipStream_t stream) {
  const float* x     = (const float*)d_in[0];
  const float* pe    = (const float*)d_in[1];
  // d_in[2] = cm (causal mask, derived analytically), d_in[3] = pm (unused)
  const float* qkv_w = (const float*)d_in[4];
  const float* qkv_b = (const float*)d_in[5];
  const float* u     = (const float*)d_in[6];
  const float* w     = (const float*)d_in[7];
  const float* out_w = (const float*)d_in[8];
  const float* out_b = (const float*)d_in[9];
  float* out = (float*)d_out;

  // workspace layout (ddbuf aliases xb/qwb: they are dead once gemm_qkv ends)
  char* wsb = (char*)d_ws;
  float*  qbuf = (float*)wsb;                        // 768x768 f32   (2.36 MB)
  ushort* owb  = (ushort*)(wsb + 2359296);           // 768x768 bf16
  ushort* obf  = (ushort*)(wsb + 3538944);           // 768x768 bf16
  ushort* kbuf = (ushort*)(wsb + 4718592);           // 2x384x768 bf16
  ushort* vbuf = (ushort*)(wsb + 5898240);           // 2x384x768 bf16
  ushort* quB  = (ushort*)(wsb + 7077888);           // 768x768 bf16
  ushort* xb   = (ushort*)(wsb + 8257536);           // 768x768 bf16 (dead after gemm_qkv)
  ushort* qwb  = (ushort*)(wsb + 9437184);           // 2304x768 bf16 (dead after gemm_qkv)
  ushort* ddb  = (ushort*)(wsb + 8257536);           // 24x384x384 bf16 (aliases xb/qwb)

  // 1) convert static operands to bf16 (one pass)
  convert_bf16<<<2880, 256, 0, stream>>>(x, qkv_w, out_w, xb, qwb, owb);

  // 2) qkv projection; epilogue emits q (f32), q+u (bf16), k/v (bf16)
  gemm_qkv<<<dim3(3 * kC / 64, kS * kB / 64), 256, 0, stream>>>(
      xb, qwb, qkv_b, u, qbuf, quB, kbuf, vbuf, kC);

  // 2b) dd = (q+u).k via MFMA, lower-triangle tiles only
  dd_gemm<<<dim3(kS / 64, kS / 64, kB * kH), 256, 0, stream>>>(
      quB, kbuf, ddb);

  // 3) fused attention (causal; only t <= s of pe is ever read)
  attn_kernel<<<kS * kB * (kH / kHPB), kHPB * 64, 0, stream>>>(
      qbuf, pe, ddb, vbuf, w, obf);

  // 4) out = o @ out_w^T + out_b   (M=768, N=768, K=768)
  gemm_bf16_lds<<<dim3(kC / 64, kS * kB / 64), 256, 0, stream>>>(
      obf, owb, out_b, out, kS * kB, kC, kC);
}

// Round 16
// 121.063 us; speedup vs baseline: 1.1207x; 1.1207x over previous
//
#include <hip/hip_runtime.h>
#include <hip/hip_bf16.h>
#include <cstdint>

constexpr int kS  = 384;
constexpr int kB  = 2;
constexpr int kC  = 768;
constexpr int kH  = 12;
constexpr int kCC = 64;
constexpr int kHPB = 4;  // heads per attention block

typedef __attribute__((ext_vector_type(8))) short short8;
typedef __attribute__((ext_vector_type(4))) float f32x4;
typedef __attribute__((ext_vector_type(4))) unsigned short u16x4;
typedef const __attribute__((address_space(1))) unsigned int glb_u32_t;
typedef __attribute__((address_space(3))) unsigned int lds_u32_t;

static __device__ __forceinline__ ushort f2bf(float f) {
  __hip_bfloat16 h = __float2bfloat16(f);
  return *reinterpret_cast<ushort*>(&h);
}
static __device__ __forceinline__ float bf2f(ushort x) {
  unsigned v = (unsigned)x << 16;
  return __builtin_bit_cast(float, v);
}

// VALU-pipe butterfly add over the 16-lane row (DPP). R13-proven (-3.6 us).
template <int CTRL>
static __device__ __forceinline__ float dpp_add(float x) {
  int xi = __builtin_bit_cast(int, x);
  int yi = __builtin_amdgcn_update_dpp(0, xi, CTRL, 0xF, 0xF, true);
  return x + __builtin_bit_cast(float, yi);
}
static __device__ __forceinline__ float row16_sum(float x) {
  x = dpp_add<0xB1>(x);
  x = dpp_add<0x4E>(x);
  x = dpp_add<0x124>(x);
  x = dpp_add<0x128>(x);
  return x;
}

// ---------------------------------------------------------------------------
// One-shot f32 -> bf16 conversion of x, qkv_w, out_w (float4-granular).
// ---------------------------------------------------------------------------
__global__ __launch_bounds__(256) void convert_bf16(
    const float* __restrict__ x, const float* __restrict__ qw,
    const float* __restrict__ ow, ushort* __restrict__ xb,
    ushort* __restrict__ qwb, ushort* __restrict__ owb) {
  int idx = blockIdx.x * 256 + threadIdx.x;
  const float* src;
  ushort* dst;
  if (idx < 147456) {
    src = x; dst = xb;
  } else if (idx < 147456 + 442368) {
    idx -= 147456; src = qw; dst = qwb;
  } else {
    idx -= 589824; src = ow; dst = owb;
  }
  f32x4 v = *reinterpret_cast<const f32x4*>(src + (size_t)idx * 4);
  u16x4 o;
  o[0] = f2bf(v[0]); o[1] = f2bf(v[1]); o[2] = f2bf(v[2]); o[3] = f2bf(v[3]);
  *reinterpret_cast<u16x4*>(dst + (size_t)idx * 4) = o;
}

// ---------------------------------------------------------------------------
// qkv-projection GEMM (R13 single-buffer) with split epilogue: q -> f32 qbuf,
// k/v -> compact bf16 buffers (L2-resident). Tile 64x64, BK=64, 4 waves 2x2.
// ---------------------------------------------------------------------------
__global__ __launch_bounds__(256) void gemm_qkv(
    const ushort* __restrict__ Abf, const ushort* __restrict__ Wbf,
    const float* __restrict__ bias, float* __restrict__ qbuf,
    ushort* __restrict__ kbuf, ushort* __restrict__ vbuf, int K) {
  __shared__ ushort As[64 * 64];
  __shared__ ushort Ws[64 * 64];
  const int tid = threadIdx.x;
  const int m0 = blockIdx.y * 64, n0 = blockIdx.x * 64;
  const int wv = tid >> 6, l = tid & 63;
  const int wr = wv >> 1, wc = wv & 1;
  const int lr = l & 15, lk = l >> 4;

  f32x4 acc[2][2] = {{{0.f, 0.f, 0.f, 0.f}, {0.f, 0.f, 0.f, 0.f}},
                     {{0.f, 0.f, 0.f, 0.f}, {0.f, 0.f, 0.f, 0.f}}};

  for (int k0 = 0; k0 < K; k0 += 64) {
    __syncthreads();
#pragma unroll
    for (int j = 0; j < 2; ++j) {
      int cid = (j * 4 + wv) * 64 + l;     // 16B chunk id, 0..511
      int r = cid >> 3, c = cid & 7;
      int cs = c ^ (r & 7);                // inverse-swizzled source chunk
      const ushort* ga = Abf + (size_t)(m0 + r) * K + k0 + cs * 8;
      __builtin_amdgcn_global_load_lds((glb_u32_t*)ga,
                                       (lds_u32_t*)&As[(cid & ~63) * 8],
                                       16, 0, 0);
      const ushort* gw = Wbf + (size_t)(n0 + r) * K + k0 + cs * 8;
      __builtin_amdgcn_global_load_lds((glb_u32_t*)gw,
                                       (lds_u32_t*)&Ws[(cid & ~63) * 8],
                                       16, 0, 0);
    }
    __syncthreads();
#pragma unroll
    for (int ks = 0; ks < 2; ++ks) {
      short8 af[2], bw[2];
#pragma unroll
      for (int f = 0; f < 2; ++f) {
        int ra = wr * 32 + f * 16 + lr;
        int ca = (ks * 4 + lk) ^ (ra & 7);
        af[f] = *reinterpret_cast<const short8*>(&As[(ra * 8 + ca) * 8]);
        int rb = wc * 32 + f * 16 + lr;
        int cb = (ks * 4 + lk) ^ (rb & 7);
        bw[f] = *reinterpret_cast<const short8*>(&Ws[(rb * 8 + cb) * 8]);
      }
#pragma unroll
      for (int fr = 0; fr < 2; ++fr)
#pragma unroll
        for (int fc = 0; fc < 2; ++fc)
          acc[fr][fc] = __builtin_amdgcn_mfma_f32_16x16x32_bf16(
              af[fr], bw[fc], acc[fr][fc], 0, 0, 0);
    }
  }

  const int seg = n0 / kC;          // 0=q, 1=k, 2=v (block-uniform)
  const int nc0 = n0 - seg * kC;
#pragma unroll
  for (int fr = 0; fr < 2; ++fr)
#pragma unroll
    for (int fc = 0; fc < 2; ++fc)
#pragma unroll
      for (int j = 0; j < 4; ++j) {
        int m = m0 + wr * 32 + fr * 16 + lk * 4 + j;
        int n = nc0 + wc * 32 + fc * 16 + lr;
        float val = acc[fr][fc][j] + bias[seg * kC + n];
        if (seg == 0) {
          qbuf[(size_t)m * kC + n] = val;
        } else {
          int t = m >> 1, bb = m & 1;
          ushort* dst = (seg == 1) ? kbuf : vbuf;
          dst[((size_t)bb * kS + t) * kC + n] = f2bf(val);
        }
      }
}

// ---------------------------------------------------------------------------
// MFMA bf16 GEMM (R13 single-buffer), f32 output + bias (out-projection).
// ---------------------------------------------------------------------------
__global__ __launch_bounds__(256) void gemm_bf16_lds(
    const ushort* __restrict__ Abf, const ushort* __restrict__ Wbf,
    const float* __restrict__ bias, float* __restrict__ Cg,
    int M, int N, int K) {
  __shared__ ushort As[64 * 64];
  __shared__ ushort Ws[64 * 64];
  const int tid = threadIdx.x;
  const int m0 = blockIdx.y * 64, n0 = blockIdx.x * 64;
  const int wv = tid >> 6, l = tid & 63;
  const int wr = wv >> 1, wc = wv & 1;
  const int lr = l & 15, lk = l >> 4;

  f32x4 acc[2][2] = {{{0.f, 0.f, 0.f, 0.f}, {0.f, 0.f, 0.f, 0.f}},
                     {{0.f, 0.f, 0.f, 0.f}, {0.f, 0.f, 0.f, 0.f}}};

  for (int k0 = 0; k0 < K; k0 += 64) {
    __syncthreads();
#pragma unroll
    for (int j = 0; j < 2; ++j) {
      int cid = (j * 4 + wv) * 64 + l;
      int r = cid >> 3, c = cid & 7;
      int cs = c ^ (r & 7);
      const ushort* ga = Abf + (size_t)(m0 + r) * K + k0 + cs * 8;
      __builtin_amdgcn_global_load_lds((glb_u32_t*)ga,
                                       (lds_u32_t*)&As[(cid & ~63) * 8],
                                       16, 0, 0);
      const ushort* gw = Wbf + (size_t)(n0 + r) * K + k0 + cs * 8;
      __builtin_amdgcn_global_load_lds((glb_u32_t*)gw,
                                       (lds_u32_t*)&Ws[(cid & ~63) * 8],
                                       16, 0, 0);
    }
    __syncthreads();
#pragma unroll
    for (int ks = 0; ks < 2; ++ks) {
      short8 af[2], bw[2];
#pragma unroll
      for (int f = 0; f < 2; ++f) {
        int ra = wr * 32 + f * 16 + lr;
        int ca = (ks * 4 + lk) ^ (ra & 7);
        af[f] = *reinterpret_cast<const short8*>(&As[(ra * 8 + ca) * 8]);
        int rb = wc * 32 + f * 16 + lr;
        int cb = (ks * 4 + lk) ^ (rb & 7);
        bw[f] = *reinterpret_cast<const short8*>(&Ws[(rb * 8 + cb) * 8]);
      }
#pragma unroll
      for (int fr = 0; fr < 2; ++fr)
#pragma unroll
        for (int fc = 0; fc < 2; ++fc)
          acc[fr][fc] = __builtin_amdgcn_mfma_f32_16x16x32_bf16(
              af[fr], bw[fc], acc[fr][fc], 0, 0, 0);
    }
  }

#pragma unroll
  for (int fr = 0; fr < 2; ++fr)
#pragma unroll
    for (int fc = 0; fc < 2; ++fc)
#pragma unroll
      for (int j = 0; j < 4; ++j) {
        int m = m0 + wr * 32 + fr * 16 + lk * 4 + j;
        int n = n0 + wc * 32 + fc * 16 + lr;
        Cg[(size_t)m * N + n] = acc[fr][fc][j] + bias[n];
      }
}

// ---------------------------------------------------------------------------
// Fused attention (R13 structure, 32-deep t unroll): two-pass, DPP reduce on
// the VALU pipe, nt pe stream, compact bf16 k/v (L2-resident). Block =
// (s, b, head-group-of-4); 256 threads, wave = one head. 8 load-batches in
// flight per lane before the consume chains (deeper latency hiding).
// ---------------------------------------------------------------------------
__global__ __launch_bounds__(256, 6) void attn_kernel(
    const float* __restrict__ qbuf, const float* __restrict__ pe,
    const ushort* __restrict__ kb, const ushort* __restrict__ vb,
    const float* __restrict__ u, const float* __restrict__ w,
    ushort* __restrict__ obf) {
  __shared__ float sc[kHPB][kS];

  const int bid = blockIdx.x;
  const int sb = bid / (kH / kHPB);   // (s,b) index, s-descending
  const int hg = bid % (kH / kHPB);   // head group
  const int s = kS - 1 - (sb >> 1);   // big-s blocks first (load balance)
  const int b = sb & 1;
  const int wave = threadIdx.x >> 6;  // head within group
  const int h = hg * kHPB + wave;
  const int lane = threadIdx.x & 63;
  const int tq = lane >> 4;           // t-subgroup
  const int cq = (lane & 15) * 4;     // channel quad
  const int ch = h * kCC + cq;
  const float scale = 0.125f;         // 1/sqrt(64)

  const int row = s * kB + b;
  const f32x4 q4 = *(const f32x4*)&qbuf[(size_t)row * kC + ch];
  const f32x4 u4 = *(const f32x4*)&u[ch];
  const f32x4 w4 = *(const f32x4*)&w[ch];
  const f32x4 qu = q4 + u4;
  const f32x4 qw = q4 + w4;

  const ushort* kbase = kb + ((size_t)b * kS) * kC + ch;
  const ushort* vbase = vb + ((size_t)b * kS) * kC + ch;
  const float* pbase = pe + ((int64_t)s * kS * kB + b) * kC + ch;
  const int pstride = kB * kC;  // 1536

  const int nfull32 = (s + 1) & ~31;  // 32-t main chunks
  const int nfull16 = (s + 1) & ~15;  // 16-t mid chunk

  // ---- pass 1: scores ----
  int t0 = 0;
  for (; t0 < nfull32; t0 += 32) {
    f32x4 p4[8];
    u16x4 kd[8];
#pragma unroll
    for (int i = 0; i < 8; ++i) {
      int t = t0 + i * 4 + tq;
      p4[i] = __builtin_nontemporal_load(
          (const f32x4*)&pbase[(int64_t)t * pstride]);
      kd[i] = *(const u16x4*)&kbase[(size_t)t * kC];
    }
#pragma unroll
    for (int i = 0; i < 8; ++i) {
      float r = qu[0] * bf2f(kd[i][0]) + qu[1] * bf2f(kd[i][1]) +
                qu[2] * bf2f(kd[i][2]) + qu[3] * bf2f(kd[i][3]) +
                qw[0] * p4[i][0] + qw[1] * p4[i][1] +
                qw[2] * p4[i][2] + qw[3] * p4[i][3];
      r = row16_sum(r);  // VALU pipe, not LDS pipe
      if ((lane & 15) == 0) sc[wave][t0 + i * 4 + tq] = r * scale;
    }
  }
  for (; t0 < nfull16; t0 += 16) {
    f32x4 p4[4];
    u16x4 kd[4];
#pragma unroll
    for (int i = 0; i < 4; ++i) {
      int t = t0 + i * 4 + tq;
      p4[i] = __builtin_nontemporal_load(
          (const f32x4*)&pbase[(int64_t)t * pstride]);
      kd[i] = *(const u16x4*)&kbase[(size_t)t * kC];
    }
#pragma unroll
    for (int i = 0; i < 4; ++i) {
      float r = qu[0] * bf2f(kd[i][0]) + qu[1] * bf2f(kd[i][1]) +
                qu[2] * bf2f(kd[i][2]) + qu[3] * bf2f(kd[i][3]) +
                qw[0] * p4[i][0] + qw[1] * p4[i][1] +
                qw[2] * p4[i][2] + qw[3] * p4[i][3];
      r = row16_sum(r);
      if ((lane & 15) == 0) sc[wave][t0 + i * 4 + tq] = r * scale;
    }
  }
  for (; t0 <= s; t0 += 4) {  // tail (<16 t's)
    int t = t0 + tq;
    int tc = (t <= s) ? t : s;  // clamp keeps loads in-bounds
    f32x4 p4 = __builtin_nontemporal_load(
        (const f32x4*)&pbase[(int64_t)tc * pstride]);
    u16x4 kd = *(const u16x4*)&kbase[(size_t)tc * kC];
    float r = qu[0] * bf2f(kd[0]) + qu[1] * bf2f(kd[1]) +
              qu[2] * bf2f(kd[2]) + qu[3] * bf2f(kd[3]) +
              qw[0] * p4[0] + qw[1] * p4[1] + qw[2] * p4[2] + qw[3] * p4[3];
    r = row16_sum(r);
    if ((lane & 15) == 0 && t <= s) sc[wave][t] = r * scale;
  }
  __syncthreads();

  // ---- softmax over t in [0, s] (wave owns its head's row) ----
  float mx = -1e30f;
  for (int t = lane; t <= s; t += 64) mx = fmaxf(mx, sc[wave][t]);
#pragma unroll
  for (int off = 32; off; off >>= 1) mx = fmaxf(mx, __shfl_xor(mx, off, 64));
  float sum = 0.f;
  for (int t = lane; t <= s; t += 64) {
    float e = __expf(sc[wave][t] - mx);
    sc[wave][t] = e;
    sum += e;
  }
#pragma unroll
  for (int off = 32; off; off >>= 1) sum += __shfl_xor(sum, off, 64);
  const float rden = 1.0f / sum;

  // ---- pass 2: o = p @ v ----
  f32x4 oa = {0.f, 0.f, 0.f, 0.f};
  t0 = 0;
  for (; t0 < nfull32; t0 += 32) {
    u16x4 vd[8];
    float p[8];
#pragma unroll
    for (int i = 0; i < 8; ++i) {
      int t = t0 + i * 4 + tq;
      vd[i] = *(const u16x4*)&vbase[(size_t)t * kC];
      p[i] = sc[wave][t];
    }
#pragma unroll
    for (int i = 0; i < 8; ++i) {
      oa[0] += p[i] * bf2f(vd[i][0]); oa[1] += p[i] * bf2f(vd[i][1]);
      oa[2] += p[i] * bf2f(vd[i][2]); oa[3] += p[i] * bf2f(vd[i][3]);
    }
  }
  for (; t0 < nfull16; t0 += 16) {
    u16x4 vd[4];
    float p[4];
#pragma unroll
    for (int i = 0; i < 4; ++i) {
      int t = t0 + i * 4 + tq;
      vd[i] = *(const u16x4*)&vbase[(size_t)t * kC];
      p[i] = sc[wave][t];
    }
#pragma unroll
    for (int i = 0; i < 4; ++i) {
      oa[0] += p[i] * bf2f(vd[i][0]); oa[1] += p[i] * bf2f(vd[i][1]);
      oa[2] += p[i] * bf2f(vd[i][2]); oa[3] += p[i] * bf2f(vd[i][3]);
    }
  }
  for (; t0 <= s; t0 += 4) {  // tail
    int t = t0 + tq;
    if (t <= s) {
      float p = sc[wave][t];
      u16x4 vd = *(const u16x4*)&vbase[(size_t)t * kC];
      oa[0] += p * bf2f(vd[0]); oa[1] += p * bf2f(vd[1]);
      oa[2] += p * bf2f(vd[2]); oa[3] += p * bf2f(vd[3]);
    }
  }
#pragma unroll
  for (int off = 16; off <= 32; off <<= 1) {
    oa[0] += __shfl_xor(oa[0], off);
    oa[1] += __shfl_xor(oa[1], off);
    oa[2] += __shfl_xor(oa[2], off);
    oa[3] += __shfl_xor(oa[3], off);
  }
  if (lane < 16) {
    u16x4 res;
    res[0] = f2bf(oa[0] * rden); res[1] = f2bf(oa[1] * rden);
    res[2] = f2bf(oa[2] * rden); res[3] = f2bf(oa[3] * rden);
    *reinterpret_cast<u16x4*>(&obf[(size_t)row * kC + ch]) = res;
  }
}

// ---------------------------------------------------------------------------
extern "C" void kernel_launch(void* const* d_in, const int* in_sizes, int n_in,
                              void* d_out, int out_size, void* d_ws,
                              size_t ws_size, hipStream_t stream) {
  const float* x     = (const float*)d_in[0];
  const float* pe    = (const float*)d_in[1];
  // d_in[2] = cm (causal mask, derived analytically), d_in[3] = pm (unused)
  const float* qkv_w = (const float*)d_in[4];
  const float* qkv_b = (const float*)d_in[5];
  const float* u     = (const float*)d_in[6];
  const float* w     = (const float*)d_in[7];
  const float* out_w = (const float*)d_in[8];
  const float* out_b = (const float*)d_in[9];
  float* out = (float*)d_out;

  // workspace layout
  char* wsb = (char*)d_ws;
  float*  qbuf = (float*)wsb;                        // 768x768  f32  (2.36 MB)
  ushort* xb   = (ushort*)(wsb + 2359296);           // 768x768  bf16
  ushort* qwb  = (ushort*)(wsb + 3538944);           // 2304x768 bf16
  ushort* owb  = (ushort*)(wsb + 7077888);           // 768x768  bf16
  ushort* obf  = (ushort*)(wsb + 8257536);           // 768x768  bf16
  ushort* kbuf = (ushort*)(wsb + 9437184);           // 2x384x768 bf16
  ushort* vbuf = (ushort*)(wsb + 10616832);          // 2x384x768 bf16

  // 1) convert static operands to bf16 (one pass)
  convert_bf16<<<2880, 256, 0, stream>>>(x, qkv_w, out_w, xb, qwb, owb);

  // 2) qkv projection with split epilogue (q f32 / k,v bf16 compact)
  gemm_qkv<<<dim3(3 * kC / 64, kS * kB / 64), 256, 0, stream>>>(
      xb, qwb, qkv_b, qbuf, kbuf, vbuf, kC);

  // 3) fused attention (causal; only t <= s of pe is ever read)
  attn_kernel<<<kS * kB * (kH / kHPB), kHPB * 64, 0, stream>>>(
      qbuf, pe, kbuf, vbuf, u, w, obf);

  // 4) out = o @ out_w^T + out_b   (M=768, N=768, K=768)
  gemm_bf16_lds<<<dim3(kC / 64, kS * kB / 64), 256, 0, stream>>>(
      obf, owb, out_b, out, kS * kB, kC, kC);
}